// Round 3
// baseline (7024.284 us; speedup 1.0000x reference)
//
#include <hip/hip_runtime.h>
#include <stdint.h>
#include <stddef.h>

// Problem constants (ESN_58317065945127)
#define B_    128
#define T_    2048
#define D_    128
#define H_    1024
#define O_    32
#define LAST_ 20

// Partition: 8 batch-blocks x 16 col-blocks = 128 WGs of 256 threads.
#define NB_   8
#define NC_   16
#define RING_ 4

typedef __bf16 bf16x8 __attribute__((ext_vector_type(8)));
typedef __bf16 bf16x4 __attribute__((ext_vector_type(4)));
typedef float  f32x4  __attribute__((ext_vector_type(4)));
typedef unsigned int u32x4 __attribute__((ext_vector_type(4)));

union Pack8  { unsigned long long u;    bf16x4 v; };
union Pack16 { unsigned long long u[2]; u32x4 d; bf16x8 v; };

__device__ __forceinline__ float tanh_fast(float s) {
    float a = fminf(fmaxf(s, -12.0f), 12.0f);
    float e = __expf(2.0f * a);
    return (e - 1.0f) / (e + 1.0f);
}

// R8: DUAL-RING EXCHANGE WITH SELF-RESCUING FAST PATH.
//
// R7 post-mortem: the intra-XCD fast path (plain store + sc0 poll) engaged
// and deadlocked to the 3s deadline -> garbage. Either sc0 loads allocate
// into L1 (stale hits forever) or CU-scope plain stores don't write through
// to L2 promptly. R8 fixes both candidate mechanisms AND makes visibility
// failure recoverable instead of fatal:
//
//   ring A (fast): publish via `global_store_dwordx2 ... sc0` (SE scope:
//     write-through L1 -> XCD L2), poll via `global_load_dwordx4 sc0 nt`
//     (bypass + no-allocate L1). Only attempted when the XCC_ID vote is
//     unanimous (cohort co-resident on one XCD).
//   ring B (proven R6 path): agent-scope atomics, ALWAYS written.
//
// Consumers poll ring A under a spin budget; on exhaustion they finish the
// step from ring B, and after 2 tripped steps go sticky-fallback. Tags make
// acceptance safe (tag-matched => correct step's data, any cache behavior);
// budgets make timeouts safe (rescue, not garbage). Worst case ~= R6 + 200us.
//
// Atomicity: plain/sc0 stores are only dword-atomic, so BOTH dwords of each
// 8B publish carry the lap tag tag(t) = ((t>>2)&1)^1 in bit 0 (bf16 elems 0
// and 2; <=1 ULP on 2 of 4 already-bf16-rounded exchange lanes). Full-h
// gating bounds drift to <=1 step; successive slot occupants differ by 4
// steps => 1 lap bit disambiguates. 0xAA poison reads tag 0 = stale for t=0.
__global__ __launch_bounds__(256, 1) void esn_persist(
    const float* __restrict__ x, const float* __restrict__ w_in,
    const float* __restrict__ w_r, __bf16* __restrict__ h_exA,
    __bf16* __restrict__ h_exB, float* __restrict__ hs,
    int* __restrict__ flags)
{
    __shared__ bf16x8 ls[2][16][128];   // 2 bufs x 16 batch-rows x 128 16B chunks = 64 KiB

    const int wg  = (int)blockIdx.x;
    const int bb  = wg & (NB_ - 1);  // cohort id (batch block)
    const int cb  = wg >> 3;
    const int tid = (int)threadIdx.x;
    const int wv  = tid >> 6;
    const int ln  = tid & 63;
    const int nn  = ln & 15;   // batch index within tile
    const int q   = ln >> 4;   // quad
    const int b0  = bb * 16;
    const int n0  = cb * 64 + wv * 16;

    // Spin deadline ~3s (guards detection + ring-B polls).
    const unsigned long long tdead =
        __builtin_amdgcn_s_memrealtime() + 300000000ull;

    // ---- XCD detection, publish leg ----
    int xcc;
    asm volatile("s_getreg_b32 %0, hwreg(HW_REG_XCC_ID)" : "=s"(xcc));
    const int mytag = 0x5A5A0000 | (xcc & 0xFF);
    if (tid == 0)
        __hip_atomic_store(flags + wg, mytag, __ATOMIC_RELAXED,
                           __HIP_MEMORY_SCOPE_AGENT);

    // ---- one-time: weight fragments into registers (A-operand layout) ----
    bf16x8 win[4];                       // w_in cols, K=128 -> 4 chunks
    #pragma unroll
    for (int c = 0; c < 4; ++c) {
        bf16x8 f;
        #pragma unroll
        for (int j = 0; j < 8; ++j)
            f[j] = (__bf16)w_in[(size_t)(c * 32 + q * 8 + j) * H_ + (n0 + nn)];
        win[c] = f;
    }
    bf16x8 wr[32];                       // w_r cols, K=1024 -> 32 chunks (128 regs)
    #pragma unroll
    for (int kc = 0; kc < 32; ++kc) {
        bf16x8 f;
        #pragma unroll
        for (int j = 0; j < 8; ++j)
            f[j] = (__bf16)w_r[(size_t)(kc * 32 + q * 8 + j) * H_ + (n0 + nn)];
        wr[kc] = f;
    }

    // ---- XCD detection, collect leg: unanimous vote enables ring A ----
    bool votefast;
    {
        int alleq = 0;
        for (;;) {
            int seen = 1; alleq = 1;
            #pragma unroll
            for (int k = 0; k < NC_; ++k) {
                int v = __hip_atomic_load(flags + (bb + 8 * k), __ATOMIC_RELAXED,
                                          __HIP_MEMORY_SCOPE_AGENT);
                seen  &= (int)((v & 0xFFFF0000) == 0x5A5A0000);
                alleq &= (int)(v == mytag);
            }
            if (seen) break;
            __builtin_amdgcn_s_sleep(8);
            if (__builtin_amdgcn_s_memrealtime() > tdead) { alleq = 0; break; }
        }
        votefast = (alleq != 0);
    }

    const float* xrow = x + (size_t)(b0 + nn) * T_ * D_ + q * 8;  // x[b][t][k]
    const size_t hrow = (size_t)(b0 + nn) * H_;

    // x prefetch (distance 1): xn = fp32 for step t+1, xf = bf16 frags for t
    f32x4 xn[8];
    bf16x8 xf[4];
    {
        #pragma unroll
        for (int c = 0; c < 4; ++c) {
            xn[2 * c]     = *(const f32x4*)(xrow + c * 32);
            xn[2 * c + 1] = *(const f32x4*)(xrow + c * 32 + 4);
        }
        #pragma unroll
        for (int c = 0; c < 4; ++c) {
            bf16x8 f;
            #pragma unroll
            for (int j = 0; j < 4; ++j) {
                f[j]     = (__bf16)xn[2 * c][j];
                f[j + 4] = (__bf16)xn[2 * c + 1][j];
            }
            xf[c] = f;
        }
    }

    float hm0 = 0.f, hm1 = 0.f, hm2 = 0.f, hm3 = 0.f;  // fp32 master h
    int ftrips = 0;                                     // fast-path trip count

    for (int t = 0; t < T_; ++t) {
        // issue x loads for t+1 NOW (fly during poll + compute)
        {
            const int tn = (t + 1 < T_) ? t + 1 : T_ - 1;
            const float* xp = xrow + (size_t)tn * D_;
            #pragma unroll
            for (int c = 0; c < 4; ++c) {
                xn[2 * c]     = *(const f32x4*)(xp + c * 32);
                xn[2 * c + 1] = *(const f32x4*)(xp + c * 32 + 4);
            }
        }

        f32x4 acc[8];
        #pragma unroll
        for (int i = 0; i < 8; ++i) acc[i] = (f32x4){0.f, 0.f, 0.f, 0.f};

        // x-projection MFMAs first: independent of the exchange.
        #pragma unroll
        for (int c = 0; c < 4; ++c)
            acc[c] = __builtin_amdgcn_mfma_f32_16x16x32_bf16(win[c], xf[c], acc[c], 0, 0, 0);

        if (t > 0) {
            const unsigned long long want1 =
                (unsigned long long)((((t - 1) >> 2) & 1) ^ 1) * 0x100000001ull;
            const int sb = (t - 1) & 1;
            const size_t slotoff =
                (size_t)((t - 1) & (RING_ - 1)) * (B_ * H_) + (size_t)b0 * H_;
            Pack16 pk[8];
            bool have = false;

            // ---- fast attempt: ring A via sc0-nt loads (XCD L2) ----
            if (votefast && ftrips < 2) {
                const __bf16* hbase = h_exA + slotoff;
                int budget = (t == 1) ? 768 : 160;
                for (;;) {
                    #pragma unroll
                    for (int i = 0; i < 8; ++i) {
                        const int p = wv * 512 + i * 64 + ln;   // 16B piece index
                        const __bf16* gp = hbase + (size_t)(p >> 7) * H_ + (p & 127) * 8;
                        asm volatile("global_load_dwordx4 %0, %1, off sc0 nt"
                                     : "=v"(pk[i].d) : "v"(gp) : "memory");
                    }
                    asm volatile("s_waitcnt vmcnt(0)"
                                 : "+v"(pk[0].d), "+v"(pk[1].d), "+v"(pk[2].d),
                                   "+v"(pk[3].d), "+v"(pk[4].d), "+v"(pk[5].d),
                                   "+v"(pk[6].d), "+v"(pk[7].d) :: "memory");
                    __builtin_amdgcn_sched_barrier(0);
                    unsigned ok = 1u;
                    #pragma unroll
                    for (int i = 0; i < 8; ++i) {
                        ok &= (unsigned)(((pk[i].u[0] ^ want1) & 0x100000001ull) == 0);
                        ok &= (unsigned)(((pk[i].u[1] ^ want1) & 0x100000001ull) == 0);
                    }
                    if (__all(ok != 0u)) { have = true; break; }
                    __builtin_amdgcn_s_sleep(1);
                    if (--budget == 0) break;
                }
                if (!have) ++ftrips;    // 2 trips -> sticky fallback
            }

            // ---- rescue / fallback: ring B via agent atomics (R6-proven) ----
            if (!have) {
                const __bf16* hbase = h_exB + slotoff;
                int spins = 0;
                for (;;) {
                    #pragma unroll
                    for (int i = 0; i < 8; ++i) {
                        const int p = wv * 512 + i * 64 + ln;
                        const unsigned long long* gp = (const unsigned long long*)
                            (hbase + (size_t)(p >> 7) * H_ + (p & 127) * 8);
                        pk[i].u[0] = __hip_atomic_load(gp, __ATOMIC_RELAXED,
                                                       __HIP_MEMORY_SCOPE_AGENT);
                        pk[i].u[1] = __hip_atomic_load(gp + 1, __ATOMIC_RELAXED,
                                                       __HIP_MEMORY_SCOPE_AGENT);
                    }
                    unsigned ok = 1u;
                    #pragma unroll
                    for (int i = 0; i < 8; ++i) {
                        ok &= (unsigned)(((pk[i].u[0] ^ want1) & 0x100000001ull) == 0);
                        ok &= (unsigned)(((pk[i].u[1] ^ want1) & 0x100000001ull) == 0);
                    }
                    if (__all(ok != 0u)) break;
                    __builtin_amdgcn_s_sleep(1);
                    if (((++spins) & 63) == 0 &&
                        __builtin_amdgcn_s_memrealtime() > tdead) break;  // anti-hang
                }
            }

            // ---- stage the loaded quarter into LDS, XOR swizzle ----
            #pragma unroll
            for (int i = 0; i < 8; ++i) {
                const int p = wv * 512 + i * 64 + ln;
                const int r = p >> 7, ch = p & 127;
                ls[sb][r][ch ^ (r & 7)] = pk[i].v;
            }

            __syncthreads();

            // ---- recurrent MFMAs from LDS, 8 accumulator chains ----
            #pragma unroll
            for (int kc = 0; kc < 32; ++kc) {
                bf16x8 a = ls[sb][nn][(kc * 4 + q) ^ (nn & 7)];
                acc[kc & 7] = __builtin_amdgcn_mfma_f32_16x16x32_bf16(wr[kc], a, acc[kc & 7], 0, 0, 0);
            }
        }

        const f32x4 asum = ((acc[0] + acc[4]) + (acc[1] + acc[5]))
                         + ((acc[2] + acc[6]) + (acc[3] + acc[7]));
        const float th0 = tanh_fast(asum[0]);
        const float th1 = tanh_fast(asum[1]);
        const float th2 = tanh_fast(asum[2]);
        const float th3 = tanh_fast(asum[3]);
        if (t == 0) {           // reference: h = tanh(xw[:,0]), no leak at t=0
            hm0 = th0; hm1 = th1; hm2 = th2; hm3 = th3;
        } else {                // h = 0.1*h + 0.9*tanh(.)
            hm0 = 0.1f * hm0 + 0.9f * th0;
            hm1 = 0.1f * hm1 + 0.9f * th1;
            hm2 = 0.1f * hm2 + 0.9f * th2;
            hm3 = 0.1f * hm3 + 0.9f * th3;
        }

        // publish 8B slice, lap tag in bit 0 of BOTH dwords — fire and forget
        {
            Pack8 p;
            p.v = (bf16x4){(__bf16)hm0, (__bf16)hm1, (__bf16)hm2, (__bf16)hm3};
            const unsigned long long tg =
                (unsigned long long)(((t >> 2) & 1) ^ 1) * 0x100000001ull;
            p.u = (p.u & ~0x100000001ull) | tg;
            const size_t poff = (size_t)(t & (RING_ - 1)) * (B_ * H_)
                                + hrow + n0 + q * 4;
            if (votefast) {     // ring A: sc0 = SE scope, write-through to XCD L2
                unsigned long long* opA = (unsigned long long*)(h_exA + poff);
                asm volatile("global_store_dwordx2 %0, %1, off sc0"
                             :: "v"(opA), "v"(p.u) : "memory");
            }
            unsigned long long* opB = (unsigned long long*)(h_exB + poff);
            __hip_atomic_store(opB, p.u, __ATOMIC_RELAXED,
                               __HIP_MEMORY_SCOPE_AGENT);
        }

        // off the critical path: tail collection + x bf16 conversion for t+1
        if (t >= T_ - LAST_) {
            f32x4* sp = (f32x4*)(hs + (size_t)(t - (T_ - LAST_)) * (B_ * H_)
                                    + hrow + n0 + q * 4);
            *sp = (f32x4){hm0, hm1, hm2, hm3};
        }
        #pragma unroll
        for (int c = 0; c < 4; ++c) {
            bf16x8 f;
            #pragma unroll
            for (int j = 0; j < 4; ++j) {
                f[j]     = (__bf16)xn[2 * c][j];
                f[j + 4] = (__bf16)xn[2 * c + 1][j];
            }
            xf[c] = f;
        }
    }
}

// Readout: out[b,:] = cat(hs)[b,:] @ W + bias.  One block per batch row.
__global__ __launch_bounds__(256) void esn_out(
    const float* __restrict__ hs, const float* __restrict__ Wm,
    const float* __restrict__ bias, float* __restrict__ out)
{
    const int b   = (int)blockIdx.x;
    const int tid = (int)threadIdx.x;
    float acc[O_];
    #pragma unroll
    for (int o = 0; o < O_; ++o) acc[o] = 0.f;

    for (int k = tid; k < LAST_ * H_; k += 256) {
        // cat order: k = t'*H + c  <->  hs[t'][b][c]
        const float hv = hs[(size_t)(k >> 10) * (B_ * H_) + (size_t)b * H_ + (k & (H_ - 1))];
        const f32x4* wp = (const f32x4*)(Wm + (size_t)k * O_);
        #pragma unroll
        for (int v = 0; v < 8; ++v) {
            f32x4 w4 = wp[v];
            acc[4 * v + 0] = fmaf(hv, w4[0], acc[4 * v + 0]);
            acc[4 * v + 1] = fmaf(hv, w4[1], acc[4 * v + 1]);
            acc[4 * v + 2] = fmaf(hv, w4[2], acc[4 * v + 2]);
            acc[4 * v + 3] = fmaf(hv, w4[3], acc[4 * v + 3]);
        }
    }

    __shared__ float red[256][O_ + 1];  // +1 pad: conflict-free column sums
    #pragma unroll
    for (int o = 0; o < O_; ++o) red[tid][o] = acc[o];
    __syncthreads();
    if (tid < O_) {
        float s = bias[tid];
        for (int i = 0; i < 256; ++i) s += red[i][tid];
        out[(size_t)b * O_ + tid] = s;
    }
}

extern "C" void kernel_launch(void* const* d_in, const int* in_sizes, int n_in,
                              void* d_out, int out_size, void* d_ws, size_t ws_size,
                              hipStream_t stream)
{
    const float* x    = (const float*)d_in[0];  // [128,2048,128]
    const float* w_in = (const float*)d_in[1];  // [128,1024]
    const float* w_r  = (const float*)d_in[2];  // [1024,1024]
    const float* Wm   = (const float*)d_in[3];  // [20480,32]
    const float* bias = (const float*)d_in[4];  // [32]
    float* out        = (float*)d_out;          // [128,32]

    const size_t flag_bytes = 4096;                                      // 128 ints used
    const size_t ring_bytes = (size_t)RING_ * B_ * H_ * sizeof(__bf16);  // 1 MiB each
    const size_t hs_bytes   = (size_t)LAST_ * B_ * H_ * sizeof(float);   // 10 MiB
    if (ws_size < flag_bytes + 2 * ring_bytes + hs_bytes) return;  // fail loud

    int*    flags = (int*)d_ws;
    __bf16* h_exA = (__bf16*)((char*)d_ws + flag_bytes);
    __bf16* h_exB = (__bf16*)((char*)d_ws + flag_bytes + ring_bytes);
    float*  hs    = (float*)((char*)d_ws + flag_bytes + 2 * ring_bytes);

    // flags = 0 (no XCD votes yet; 0 fails the 0x5A5A pattern check).
    // Rings = 0xAA: tag bit 0 = 0 = stale for t=0 (t=0 publishes tag 1).
    hipMemsetAsync(flags, 0x00, flag_bytes, stream);
    hipMemsetAsync(h_exA, 0xAA, 2 * ring_bytes, stream);

    hipLaunchKernelGGL(esn_persist, dim3(NB_ * NC_), dim3(256), 0, stream,
                       x, w_in, w_r, h_exA, h_exB, hs, flags);
    hipLaunchKernelGGL(esn_out, dim3(B_), dim3(256), 0, stream,
                       hs, Wm, bias, out);
}

// Round 5
// 6650.159 us; speedup vs baseline: 1.0563x; 1.0563x over previous
//
#include <hip/hip_runtime.h>
#include <stdint.h>
#include <stddef.h>

// Problem constants (ESN_58317065945127)
#define B_    128
#define T_    2048
#define D_    128
#define H_    1024
#define O_    32
#define LAST_ 20

// Partition: 8 batch-blocks x 16 col-blocks = 128 WGs of 256 threads.
#define NB_   8
#define NC_   16
#define RING_ 4
#define TWARM_ 8      // steps [1,TWARM): ring B only (absorbs startup skew)

typedef __bf16 bf16x8 __attribute__((ext_vector_type(8)));
typedef __bf16 bf16x4 __attribute__((ext_vector_type(4)));
typedef float  f32x4  __attribute__((ext_vector_type(4)));
typedef unsigned int u32x4 __attribute__((ext_vector_type(4)));

union Pack8  { unsigned long long u;    bf16x4 v; };
union Pack16 { unsigned long long u[2]; u32x4 d; bf16x8 v; };

__device__ __forceinline__ float tanh_fast(float s) {
    float a = fminf(fmaxf(s, -12.0f), 12.0f);
    float e = __expf(2.0f * a);
    return (e - 1.0f) / (e + 1.0f);
}

// R9 (resubmit — previous round died to container-acquire infra failure,
// the kernel never ran): DUAL-RING, WARMUP-PARTITIONED, NON-STICKY.
//
// R8 post-mortem: ring A (sc0 store -> XCD L2 -> sc0 nt poll) WORKS
// (FETCH_SIZE 346->86 MB proves polls were L2-served), but the sticky
// fallback (2 budget trips ever -> ring B forever) let warmup skew at t=1
// (uncoalesced weight-gather completion times differ by ~100us across WGs)
// permanently demote some WGs to ring B. Full-h gating means ONE ring-B WG
// per cohort sets the cohort pace -> R6 latency + dual-ring overhead = +15%.
//
// R9 removes the failure mode structurally:
//   t in [1, TWARM): ring B only (R6-proven protocol absorbs ALL startup
//     skew; by the time any WG reaches t>=2, every producer has finished
//     weight loads — full-h gating bounds drift to <=1 step).
//   t >= TWARM: ring A poll (no sleep, budget 512 ~ 50x steady-state skew);
//     on exhaustion, rescue THIS STEP from ring B and continue — never
//     sticky. Producers always write both rings (ring A first).
//
// Tags make acceptance safe under any cache behavior (tag-matched 8B word
// => that step's data; both dwords tagged since plain stores are only
// dword-atomic; lap parity disambiguates the 4-step slot reuse distance).
// Budgets make timeouts safe (rescue, not garbage).
__global__ __launch_bounds__(256, 1) void esn_persist(
    const float* __restrict__ x, const float* __restrict__ w_in,
    const float* __restrict__ w_r, __bf16* __restrict__ h_exA,
    __bf16* __restrict__ h_exB, float* __restrict__ hs,
    int* __restrict__ flags)
{
    __shared__ bf16x8 ls[2][16][128];   // 2 bufs x 16 batch-rows x 128 16B chunks = 64 KiB

    const int wg  = (int)blockIdx.x;
    const int bb  = wg & (NB_ - 1);  // cohort id (batch block)
    const int cb  = wg >> 3;
    const int tid = (int)threadIdx.x;
    const int wv  = tid >> 6;
    const int ln  = tid & 63;
    const int nn  = ln & 15;   // batch index within tile
    const int q   = ln >> 4;   // quad
    const int b0  = bb * 16;
    const int n0  = cb * 64 + wv * 16;

    // Spin deadline ~3s (guards detection + ring-B polls).
    const unsigned long long tdead =
        __builtin_amdgcn_s_memrealtime() + 300000000ull;

    // ---- XCD detection, publish leg ----
    int xcc;
    asm volatile("s_getreg_b32 %0, hwreg(HW_REG_XCC_ID)" : "=s"(xcc));
    const int mytag = 0x5A5A0000 | (xcc & 0xFF);
    if (tid == 0)
        __hip_atomic_store(flags + wg, mytag, __ATOMIC_RELAXED,
                           __HIP_MEMORY_SCOPE_AGENT);

    // ---- one-time: weight fragments into registers (A-operand layout) ----
    bf16x8 win[4];                       // w_in cols, K=128 -> 4 chunks
    #pragma unroll
    for (int c = 0; c < 4; ++c) {
        bf16x8 f;
        #pragma unroll
        for (int j = 0; j < 8; ++j)
            f[j] = (__bf16)w_in[(size_t)(c * 32 + q * 8 + j) * H_ + (n0 + nn)];
        win[c] = f;
    }
    bf16x8 wr[32];                       // w_r cols, K=1024 -> 32 chunks (128 regs)
    #pragma unroll
    for (int kc = 0; kc < 32; ++kc) {
        bf16x8 f;
        #pragma unroll
        for (int j = 0; j < 8; ++j)
            f[j] = (__bf16)w_r[(size_t)(kc * 32 + q * 8 + j) * H_ + (n0 + nn)];
        wr[kc] = f;
    }

    // ---- XCD detection, collect leg: unanimous vote enables ring A ----
    bool votefast;
    {
        int alleq = 0;
        for (;;) {
            int seen = 1; alleq = 1;
            #pragma unroll
            for (int k = 0; k < NC_; ++k) {
                int v = __hip_atomic_load(flags + (bb + 8 * k), __ATOMIC_RELAXED,
                                          __HIP_MEMORY_SCOPE_AGENT);
                seen  &= (int)((v & 0xFFFF0000) == 0x5A5A0000);
                alleq &= (int)(v == mytag);
            }
            if (seen) break;
            __builtin_amdgcn_s_sleep(8);
            if (__builtin_amdgcn_s_memrealtime() > tdead) { alleq = 0; break; }
        }
        votefast = (alleq != 0);
    }

    const float* xrow = x + (size_t)(b0 + nn) * T_ * D_ + q * 8;  // x[b][t][k]
    const size_t hrow = (size_t)(b0 + nn) * H_;

    // x prefetch (distance 1): xn = fp32 for step t+1, xf = bf16 frags for t
    f32x4 xn[8];
    bf16x8 xf[4];
    {
        #pragma unroll
        for (int c = 0; c < 4; ++c) {
            xn[2 * c]     = *(const f32x4*)(xrow + c * 32);
            xn[2 * c + 1] = *(const f32x4*)(xrow + c * 32 + 4);
        }
        #pragma unroll
        for (int c = 0; c < 4; ++c) {
            bf16x8 f;
            #pragma unroll
            for (int j = 0; j < 4; ++j) {
                f[j]     = (__bf16)xn[2 * c][j];
                f[j + 4] = (__bf16)xn[2 * c + 1][j];
            }
            xf[c] = f;
        }
    }

    float hm0 = 0.f, hm1 = 0.f, hm2 = 0.f, hm3 = 0.f;  // fp32 master h

    for (int t = 0; t < T_; ++t) {
        // issue x loads for t+1 NOW (fly during poll + compute)
        {
            const int tn = (t + 1 < T_) ? t + 1 : T_ - 1;
            const float* xp = xrow + (size_t)tn * D_;
            #pragma unroll
            for (int c = 0; c < 4; ++c) {
                xn[2 * c]     = *(const f32x4*)(xp + c * 32);
                xn[2 * c + 1] = *(const f32x4*)(xp + c * 32 + 4);
            }
        }

        f32x4 acc[8];
        #pragma unroll
        for (int i = 0; i < 8; ++i) acc[i] = (f32x4){0.f, 0.f, 0.f, 0.f};

        // x-projection MFMAs first: independent of the exchange.
        #pragma unroll
        for (int c = 0; c < 4; ++c)
            acc[c] = __builtin_amdgcn_mfma_f32_16x16x32_bf16(win[c], xf[c], acc[c], 0, 0, 0);

        if (t > 0) {
            const unsigned long long want1 =
                (unsigned long long)((((t - 1) >> 2) & 1) ^ 1) * 0x100000001ull;
            const int sb = (t - 1) & 1;
            const size_t slotoff =
                (size_t)((t - 1) & (RING_ - 1)) * (B_ * H_) + (size_t)b0 * H_;
            Pack16 pk[8];
            bool have = false;

            // ---- steady state: ring A via sc0-nt loads (XCD L2), hot spin ----
            if (votefast && t >= TWARM_) {
                const __bf16* hbase = h_exA + slotoff;
                int budget = 512;
                for (;;) {
                    #pragma unroll
                    for (int i = 0; i < 8; ++i) {
                        const int p = wv * 512 + i * 64 + ln;   // 16B piece index
                        const __bf16* gp = hbase + (size_t)(p >> 7) * H_ + (p & 127) * 8;
                        asm volatile("global_load_dwordx4 %0, %1, off sc0 nt"
                                     : "=v"(pk[i].d) : "v"(gp) : "memory");
                    }
                    asm volatile("s_waitcnt vmcnt(0)"
                                 : "+v"(pk[0].d), "+v"(pk[1].d), "+v"(pk[2].d),
                                   "+v"(pk[3].d), "+v"(pk[4].d), "+v"(pk[5].d),
                                   "+v"(pk[6].d), "+v"(pk[7].d) :: "memory");
                    __builtin_amdgcn_sched_barrier(0);
                    unsigned ok = 1u;
                    #pragma unroll
                    for (int i = 0; i < 8; ++i) {
                        ok &= (unsigned)(((pk[i].u[0] ^ want1) & 0x100000001ull) == 0);
                        ok &= (unsigned)(((pk[i].u[1] ^ want1) & 0x100000001ull) == 0);
                    }
                    if (__all(ok != 0u)) { have = true; break; }
                    if (--budget == 0) break;   // rescue below; NEVER sticky
                }
            }

            // ---- warmup / rescue: ring B via agent atomics (R6-proven) ----
            if (!have) {
                const __bf16* hbase = h_exB + slotoff;
                int spins = 0;
                for (;;) {
                    #pragma unroll
                    for (int i = 0; i < 8; ++i) {
                        const int p = wv * 512 + i * 64 + ln;
                        const unsigned long long* gp = (const unsigned long long*)
                            (hbase + (size_t)(p >> 7) * H_ + (p & 127) * 8);
                        pk[i].u[0] = __hip_atomic_load(gp, __ATOMIC_RELAXED,
                                                       __HIP_MEMORY_SCOPE_AGENT);
                        pk[i].u[1] = __hip_atomic_load(gp + 1, __ATOMIC_RELAXED,
                                                       __HIP_MEMORY_SCOPE_AGENT);
                    }
                    unsigned ok = 1u;
                    #pragma unroll
                    for (int i = 0; i < 8; ++i) {
                        ok &= (unsigned)(((pk[i].u[0] ^ want1) & 0x100000001ull) == 0);
                        ok &= (unsigned)(((pk[i].u[1] ^ want1) & 0x100000001ull) == 0);
                    }
                    if (__all(ok != 0u)) break;
                    __builtin_amdgcn_s_sleep(1);
                    if (((++spins) & 63) == 0 &&
                        __builtin_amdgcn_s_memrealtime() > tdead) break;  // anti-hang
                }
            }

            // ---- stage the loaded quarter into LDS, XOR swizzle ----
            #pragma unroll
            for (int i = 0; i < 8; ++i) {
                const int p = wv * 512 + i * 64 + ln;
                const int r = p >> 7, ch = p & 127;
                ls[sb][r][ch ^ (r & 7)] = pk[i].v;
            }

            __syncthreads();

            // ---- recurrent MFMAs from LDS, 8 accumulator chains ----
            #pragma unroll
            for (int kc = 0; kc < 32; ++kc) {
                bf16x8 a = ls[sb][nn][(kc * 4 + q) ^ (nn & 7)];
                acc[kc & 7] = __builtin_amdgcn_mfma_f32_16x16x32_bf16(wr[kc], a, acc[kc & 7], 0, 0, 0);
            }
        }

        const f32x4 asum = ((acc[0] + acc[4]) + (acc[1] + acc[5]))
                         + ((acc[2] + acc[6]) + (acc[3] + acc[7]));
        const float th0 = tanh_fast(asum[0]);
        const float th1 = tanh_fast(asum[1]);
        const float th2 = tanh_fast(asum[2]);
        const float th3 = tanh_fast(asum[3]);
        if (t == 0) {           // reference: h = tanh(xw[:,0]), no leak at t=0
            hm0 = th0; hm1 = th1; hm2 = th2; hm3 = th3;
        } else {                // h = 0.1*h + 0.9*tanh(.)
            hm0 = 0.1f * hm0 + 0.9f * th0;
            hm1 = 0.1f * hm1 + 0.9f * th1;
            hm2 = 0.1f * hm2 + 0.9f * th2;
            hm3 = 0.1f * hm3 + 0.9f * th3;
        }

        // publish 8B slice, lap tag in bit 0 of BOTH dwords — fire and forget
        {
            Pack8 p;
            p.v = (bf16x4){(__bf16)hm0, (__bf16)hm1, (__bf16)hm2, (__bf16)hm3};
            const unsigned long long tg =
                (unsigned long long)(((t >> 2) & 1) ^ 1) * 0x100000001ull;
            p.u = (p.u & ~0x100000001ull) | tg;
            const size_t poff = (size_t)(t & (RING_ - 1)) * (B_ * H_)
                                + hrow + n0 + q * 4;
            if (votefast) {     // ring A first: earliest L2 visibility
                unsigned long long* opA = (unsigned long long*)(h_exA + poff);
                asm volatile("global_store_dwordx2 %0, %1, off sc0"
                             :: "v"(opA), "v"(p.u) : "memory");
            }
            unsigned long long* opB = (unsigned long long*)(h_exB + poff);
            __hip_atomic_store(opB, p.u, __ATOMIC_RELAXED,
                               __HIP_MEMORY_SCOPE_AGENT);
        }

        // off the critical path: tail collection + x bf16 conversion for t+1
        if (t >= T_ - LAST_) {
            f32x4* sp = (f32x4*)(hs + (size_t)(t - (T_ - LAST_)) * (B_ * H_)
                                    + hrow + n0 + q * 4);
            *sp = (f32x4){hm0, hm1, hm2, hm3};
        }
        #pragma unroll
        for (int c = 0; c < 4; ++c) {
            bf16x8 f;
            #pragma unroll
            for (int j = 0; j < 4; ++j) {
                f[j]     = (__bf16)xn[2 * c][j];
                f[j + 4] = (__bf16)xn[2 * c + 1][j];
            }
            xf[c] = f;
        }
    }
}

// Readout: out[b,:] = cat(hs)[b,:] @ W + bias.  One block per batch row.
__global__ __launch_bounds__(256) void esn_out(
    const float* __restrict__ hs, const float* __restrict__ Wm,
    const float* __restrict__ bias, float* __restrict__ out)
{
    const int b   = (int)blockIdx.x;
    const int tid = (int)threadIdx.x;
    float acc[O_];
    #pragma unroll
    for (int o = 0; o < O_; ++o) acc[o] = 0.f;

    for (int k = tid; k < LAST_ * H_; k += 256) {
        // cat order: k = t'*H + c  <->  hs[t'][b][c]
        const float hv = hs[(size_t)(k >> 10) * (B_ * H_) + (size_t)b * H_ + (k & (H_ - 1))];
        const f32x4* wp = (const f32x4*)(Wm + (size_t)k * O_);
        #pragma unroll
        for (int v = 0; v < 8; ++v) {
            f32x4 w4 = wp[v];
            acc[4 * v + 0] = fmaf(hv, w4[0], acc[4 * v + 0]);
            acc[4 * v + 1] = fmaf(hv, w4[1], acc[4 * v + 1]);
            acc[4 * v + 2] = fmaf(hv, w4[2], acc[4 * v + 2]);
            acc[4 * v + 3] = fmaf(hv, w4[3], acc[4 * v + 3]);
        }
    }

    __shared__ float red[256][O_ + 1];  // +1 pad: conflict-free column sums
    #pragma unroll
    for (int o = 0; o < O_; ++o) red[tid][o] = acc[o];
    __syncthreads();
    if (tid < O_) {
        float s = bias[tid];
        for (int i = 0; i < 256; ++i) s += red[i][tid];
        out[(size_t)b * O_ + tid] = s;
    }
}

extern "C" void kernel_launch(void* const* d_in, const int* in_sizes, int n_in,
                              void* d_out, int out_size, void* d_ws, size_t ws_size,
                              hipStream_t stream)
{
    const float* x    = (const float*)d_in[0];  // [128,2048,128]
    const float* w_in = (const float*)d_in[1];  // [128,1024]
    const float* w_r  = (const float*)d_in[2];  // [1024,1024]
    const float* Wm   = (const float*)d_in[3];  // [20480,32]
    const float* bias = (const float*)d_in[4];  // [32]
    float* out        = (float*)d_out;          // [128,32]

    const size_t flag_bytes = 4096;                                      // 128 ints used
    const size_t ring_bytes = (size_t)RING_ * B_ * H_ * sizeof(__bf16);  // 1 MiB each
    const size_t hs_bytes   = (size_t)LAST_ * B_ * H_ * sizeof(float);   // 10 MiB
    if (ws_size < flag_bytes + 2 * ring_bytes + hs_bytes) return;  // fail loud

    int*    flags = (int*)d_ws;
    __bf16* h_exA = (__bf16*)((char*)d_ws + flag_bytes);
    __bf16* h_exB = (__bf16*)((char*)d_ws + flag_bytes + ring_bytes);
    float*  hs    = (float*)((char*)d_ws + flag_bytes + 2 * ring_bytes);

    // flags = 0 (no XCD votes yet; 0 fails the 0x5A5A pattern check).
    // Rings = 0xAA: tag bit 0 = 0 = stale for t=0 (t=0 publishes tag 1).
    hipMemsetAsync(flags, 0x00, flag_bytes, stream);
    hipMemsetAsync(h_exA, 0xAA, 2 * ring_bytes, stream);

    hipLaunchKernelGGL(esn_persist, dim3(NB_ * NC_), dim3(256), 0, stream,
                       x, w_in, w_r, h_exA, h_exB, hs, flags);
    hipLaunchKernelGGL(esn_out, dim3(B_), dim3(256), 0, stream,
                       hs, Wm, bias, out);
}

// Round 6
// 6551.453 us; speedup vs baseline: 1.0722x; 1.0151x over previous
//
#include <hip/hip_runtime.h>
#include <stdint.h>
#include <stddef.h>

// Problem constants (ESN_58317065945127)
#define B_    128
#define T_    2048
#define D_    128
#define H_    1024
#define O_    32
#define LAST_ 20

// Partition: 8 batch-blocks x 16 col-blocks = 128 WGs of 256 threads.
#define NB_   8
#define NC_   16
#define RING_ 4
#define TWARM_ 8      // steps [1,TWARM): ring B full-poll only (startup skew)

typedef __bf16 bf16x8 __attribute__((ext_vector_type(8)));
typedef __bf16 bf16x4 __attribute__((ext_vector_type(4)));
typedef float  f32x4  __attribute__((ext_vector_type(4)));
typedef unsigned int u32x4 __attribute__((ext_vector_type(4)));

union Pack8  { unsigned long long u;    bf16x4 v; };
union Pack16 { unsigned long long u[2]; u32x4 d; bf16x8 v; };

__device__ __forceinline__ float tanh_fast(float s) {
    float a = fminf(fmaxf(s, -12.0f), 12.0f);
    float e = __expf(2.0f * a);
    return (e - 1.0f) / (e + 1.0f);
}

// R10: SENTINEL-FIRST DISCOVERY.
//
// R9 post-mortem: ring A (sc0 -> XCD L2) works mechanically (FETCH 346->87MB)
// but pace didn't improve. Cause: FULL-DATA POLLING — every consumer WG
// reloads its 32KB quarter per poll iteration; 16 WGs/cohort hot-spinning =
// ~4.3 TB/s demanded of ONE XCD L2 (its ceiling). The polls saturate the
// tier serving them, inflating their own latency and store visibility.
// (VALUBusy 10.5% = ~20 tag-check iters/step = ~2.4us of the 3.16us step.)
// R6's 346MB fabric fetch was the same disease at LLC tier.
//
// R10 splits discovery from transfer:
//   phase 1 (poll): lane l watches ONE sentinel word — the (row 15, q=3)
//     word that producer wave l=(cb',wv') publishes as part of its normal
//     payload (written by its lane 63). One dwordx2 load per consumer wave
//     covers all 64 producer waves: ~2KB of hot L2 lines per iteration
//     instead of 32KB -> 64x less poll bandwidth; L2 serves at idle latency.
//   phase 2 (fetch): payload loaded ONCE, per-word tags verified (lanes of
//     a producer wave may complete out of order -> rare refetch, deadline-
//     bounded). Tag-matched data is always correct data.
//   warmup t<TWARM and rescue (sentinel budget exhausted): ring B full poll
//     (R6-proven), never sticky.
// Producers: unchanged dual publish (ring A sc0 if votefast, ring B agent).
__global__ __launch_bounds__(256, 1) void esn_persist(
    const float* __restrict__ x, const float* __restrict__ w_in,
    const float* __restrict__ w_r, __bf16* __restrict__ h_exA,
    __bf16* __restrict__ h_exB, float* __restrict__ hs,
    int* __restrict__ flags)
{
    __shared__ bf16x8 ls[2][16][128];   // 2 bufs x 16 batch-rows x 128 16B chunks = 64 KiB

    const int wg  = (int)blockIdx.x;
    const int bb  = wg & (NB_ - 1);  // cohort id (batch block)
    const int cb  = wg >> 3;
    const int tid = (int)threadIdx.x;
    const int wv  = tid >> 6;
    const int ln  = tid & 63;
    const int nn  = ln & 15;   // batch index within tile
    const int q   = ln >> 4;   // quad
    const int b0  = bb * 16;
    const int n0  = cb * 64 + wv * 16;

    // Spin deadline ~3s (guards detection + ring-B polls + verify loops).
    const unsigned long long tdead =
        __builtin_amdgcn_s_memrealtime() + 300000000ull;

    // ---- XCD detection, publish leg ----
    int xcc;
    asm volatile("s_getreg_b32 %0, hwreg(HW_REG_XCC_ID)" : "=s"(xcc));
    const int mytag = 0x5A5A0000 | (xcc & 0xFF);
    if (tid == 0)
        __hip_atomic_store(flags + wg, mytag, __ATOMIC_RELAXED,
                           __HIP_MEMORY_SCOPE_AGENT);

    // ---- one-time: weight fragments into registers (A-operand layout) ----
    bf16x8 win[4];                       // w_in cols, K=128 -> 4 chunks
    #pragma unroll
    for (int c = 0; c < 4; ++c) {
        bf16x8 f;
        #pragma unroll
        for (int j = 0; j < 8; ++j)
            f[j] = (__bf16)w_in[(size_t)(c * 32 + q * 8 + j) * H_ + (n0 + nn)];
        win[c] = f;
    }
    bf16x8 wr[32];                       // w_r cols, K=1024 -> 32 chunks (128 regs)
    #pragma unroll
    for (int kc = 0; kc < 32; ++kc) {
        bf16x8 f;
        #pragma unroll
        for (int j = 0; j < 8; ++j)
            f[j] = (__bf16)w_r[(size_t)(kc * 32 + q * 8 + j) * H_ + (n0 + nn)];
        wr[kc] = f;
    }

    // ---- XCD detection, collect leg: unanimous vote enables ring A ----
    bool votefast;
    {
        int alleq = 0;
        for (;;) {
            int seen = 1; alleq = 1;
            #pragma unroll
            for (int k = 0; k < NC_; ++k) {
                int v = __hip_atomic_load(flags + (bb + 8 * k), __ATOMIC_RELAXED,
                                          __HIP_MEMORY_SCOPE_AGENT);
                seen  &= (int)((v & 0xFFFF0000) == 0x5A5A0000);
                alleq &= (int)(v == mytag);
            }
            if (seen) break;
            __builtin_amdgcn_s_sleep(8);
            if (__builtin_amdgcn_s_memrealtime() > tdead) { alleq = 0; break; }
        }
        votefast = (alleq != 0);
    }

    const float* xrow = x + (size_t)(b0 + nn) * T_ * D_ + q * 8;  // x[b][t][k]
    const size_t hrow = (size_t)(b0 + nn) * H_;

    // sentinel element offset within a ring slot's cohort block:
    // row 15, col (ln>>2)*64 + (ln&3)*16 + 12  (the q=3 word of producer
    // wave (cb'=ln>>2, wv'=ln&3), written by its lane 63). 8B-aligned.
    const int scol = (ln >> 2) * 64 + (ln & 3) * 16 + 12;

    // x prefetch (distance 1): xn = fp32 for step t+1, xf = bf16 frags for t
    f32x4 xn[8];
    bf16x8 xf[4];
    {
        #pragma unroll
        for (int c = 0; c < 4; ++c) {
            xn[2 * c]     = *(const f32x4*)(xrow + c * 32);
            xn[2 * c + 1] = *(const f32x4*)(xrow + c * 32 + 4);
        }
        #pragma unroll
        for (int c = 0; c < 4; ++c) {
            bf16x8 f;
            #pragma unroll
            for (int j = 0; j < 4; ++j) {
                f[j]     = (__bf16)xn[2 * c][j];
                f[j + 4] = (__bf16)xn[2 * c + 1][j];
            }
            xf[c] = f;
        }
    }

    float hm0 = 0.f, hm1 = 0.f, hm2 = 0.f, hm3 = 0.f;  // fp32 master h

    for (int t = 0; t < T_; ++t) {
        // issue x loads for t+1 NOW (fly during poll + compute)
        {
            const int tn = (t + 1 < T_) ? t + 1 : T_ - 1;
            const float* xp = xrow + (size_t)tn * D_;
            #pragma unroll
            for (int c = 0; c < 4; ++c) {
                xn[2 * c]     = *(const f32x4*)(xp + c * 32);
                xn[2 * c + 1] = *(const f32x4*)(xp + c * 32 + 4);
            }
        }

        f32x4 acc[8];
        #pragma unroll
        for (int i = 0; i < 8; ++i) acc[i] = (f32x4){0.f, 0.f, 0.f, 0.f};

        // x-projection MFMAs first: independent of the exchange.
        #pragma unroll
        for (int c = 0; c < 4; ++c)
            acc[c] = __builtin_amdgcn_mfma_f32_16x16x32_bf16(win[c], xf[c], acc[c], 0, 0, 0);

        if (t > 0) {
            const unsigned long long want1 =
                (unsigned long long)((((t - 1) >> 2) & 1) ^ 1) * 0x100000001ull;
            const int sb = (t - 1) & 1;
            const size_t slotoff =
                (size_t)((t - 1) & (RING_ - 1)) * (B_ * H_) + (size_t)b0 * H_;
            Pack16 pk[8];
            bool have = false;

            if (t >= TWARM_) {
                // ---- phase 1: sentinel poll (8B/lane, 64x less BW) ----
                bool sent = false;
                int budget = 1024;
                if (votefast) {
                    const unsigned long long* sp = (const unsigned long long*)
                        (h_exA + slotoff + 15 * H_ + scol);
                    for (;;) {
                        unsigned long long s;
                        asm volatile("global_load_dwordx2 %0, %1, off sc0 nt"
                                     : "=v"(s) : "v"(sp) : "memory");
                        asm volatile("s_waitcnt vmcnt(0)" : "+v"(s) :: "memory");
                        if (__all(((s ^ want1) & 0x100000001ull) == 0)) { sent = true; break; }
                        if (--budget == 0) break;
                    }
                } else {
                    const unsigned long long* sp = (const unsigned long long*)
                        (h_exB + slotoff + 15 * H_ + scol);
                    for (;;) {
                        unsigned long long s = __hip_atomic_load(sp, __ATOMIC_RELAXED,
                                                                 __HIP_MEMORY_SCOPE_AGENT);
                        if (__all(((s ^ want1) & 0x100000001ull) == 0)) { sent = true; break; }
                        if (--budget == 0) break;
                    }
                }

                // ---- phase 2: one-shot payload fetch + tag verify ----
                if (sent) {
                    int spins = 0;
                    for (;;) {
                        if (votefast) {
                            #pragma unroll
                            for (int i = 0; i < 8; ++i) {
                                const int p = wv * 512 + i * 64 + ln;   // 16B piece
                                const __bf16* gp = h_exA + slotoff
                                    + (size_t)(p >> 7) * H_ + (p & 127) * 8;
                                asm volatile("global_load_dwordx4 %0, %1, off sc0 nt"
                                             : "=v"(pk[i].d) : "v"(gp) : "memory");
                            }
                            asm volatile("s_waitcnt vmcnt(0)"
                                         : "+v"(pk[0].d), "+v"(pk[1].d), "+v"(pk[2].d),
                                           "+v"(pk[3].d), "+v"(pk[4].d), "+v"(pk[5].d),
                                           "+v"(pk[6].d), "+v"(pk[7].d) :: "memory");
                            __builtin_amdgcn_sched_barrier(0);
                        } else {
                            #pragma unroll
                            for (int i = 0; i < 8; ++i) {
                                const int p = wv * 512 + i * 64 + ln;
                                const unsigned long long* gp = (const unsigned long long*)
                                    (h_exB + slotoff + (size_t)(p >> 7) * H_ + (p & 127) * 8);
                                pk[i].u[0] = __hip_atomic_load(gp, __ATOMIC_RELAXED,
                                                               __HIP_MEMORY_SCOPE_AGENT);
                                pk[i].u[1] = __hip_atomic_load(gp + 1, __ATOMIC_RELAXED,
                                                               __HIP_MEMORY_SCOPE_AGENT);
                            }
                        }
                        unsigned ok = 1u;
                        #pragma unroll
                        for (int i = 0; i < 8; ++i) {
                            ok &= (unsigned)(((pk[i].u[0] ^ want1) & 0x100000001ull) == 0);
                            ok &= (unsigned)(((pk[i].u[1] ^ want1) & 0x100000001ull) == 0);
                        }
                        if (__all(ok != 0u)) { have = true; break; }
                        if (((++spins) & 63) == 0 &&
                            __builtin_amdgcn_s_memrealtime() > tdead) break;  // anti-hang
                    }
                }
            }

            // ---- warmup / rescue: ring B full poll (R6-proven) ----
            if (!have) {
                const __bf16* hbase = h_exB + slotoff;
                int spins = 0;
                for (;;) {
                    #pragma unroll
                    for (int i = 0; i < 8; ++i) {
                        const int p = wv * 512 + i * 64 + ln;
                        const unsigned long long* gp = (const unsigned long long*)
                            (hbase + (size_t)(p >> 7) * H_ + (p & 127) * 8);
                        pk[i].u[0] = __hip_atomic_load(gp, __ATOMIC_RELAXED,
                                                       __HIP_MEMORY_SCOPE_AGENT);
                        pk[i].u[1] = __hip_atomic_load(gp + 1, __ATOMIC_RELAXED,
                                                       __HIP_MEMORY_SCOPE_AGENT);
                    }
                    unsigned ok = 1u;
                    #pragma unroll
                    for (int i = 0; i < 8; ++i) {
                        ok &= (unsigned)(((pk[i].u[0] ^ want1) & 0x100000001ull) == 0);
                        ok &= (unsigned)(((pk[i].u[1] ^ want1) & 0x100000001ull) == 0);
                    }
                    if (__all(ok != 0u)) break;
                    __builtin_amdgcn_s_sleep(1);
                    if (((++spins) & 63) == 0 &&
                        __builtin_amdgcn_s_memrealtime() > tdead) break;  // anti-hang
                }
            }

            // ---- stage the loaded quarter into LDS, XOR swizzle ----
            #pragma unroll
            for (int i = 0; i < 8; ++i) {
                const int p = wv * 512 + i * 64 + ln;
                const int r = p >> 7, ch = p & 127;
                ls[sb][r][ch ^ (r & 7)] = pk[i].v;
            }

            __syncthreads();

            // ---- recurrent MFMAs from LDS, 8 accumulator chains ----
            #pragma unroll
            for (int kc = 0; kc < 32; ++kc) {
                bf16x8 a = ls[sb][nn][(kc * 4 + q) ^ (nn & 7)];
                acc[kc & 7] = __builtin_amdgcn_mfma_f32_16x16x32_bf16(wr[kc], a, acc[kc & 7], 0, 0, 0);
            }
        }

        const f32x4 asum = ((acc[0] + acc[4]) + (acc[1] + acc[5]))
                         + ((acc[2] + acc[6]) + (acc[3] + acc[7]));
        const float th0 = tanh_fast(asum[0]);
        const float th1 = tanh_fast(asum[1]);
        const float th2 = tanh_fast(asum[2]);
        const float th3 = tanh_fast(asum[3]);
        if (t == 0) {           // reference: h = tanh(xw[:,0]), no leak at t=0
            hm0 = th0; hm1 = th1; hm2 = th2; hm3 = th3;
        } else {                // h = 0.1*h + 0.9*tanh(.)
            hm0 = 0.1f * hm0 + 0.9f * th0;
            hm1 = 0.1f * hm1 + 0.9f * th1;
            hm2 = 0.1f * hm2 + 0.9f * th2;
            hm3 = 0.1f * hm3 + 0.9f * th3;
        }

        // publish 8B slice, lap tag in bit 0 of BOTH dwords — fire and forget
        {
            Pack8 p;
            p.v = (bf16x4){(__bf16)hm0, (__bf16)hm1, (__bf16)hm2, (__bf16)hm3};
            const unsigned long long tg =
                (unsigned long long)(((t >> 2) & 1) ^ 1) * 0x100000001ull;
            p.u = (p.u & ~0x100000001ull) | tg;
            const size_t poff = (size_t)(t & (RING_ - 1)) * (B_ * H_)
                                + hrow + n0 + q * 4;
            if (votefast) {     // ring A first: earliest L2 visibility
                unsigned long long* opA = (unsigned long long*)(h_exA + poff);
                asm volatile("global_store_dwordx2 %0, %1, off sc0"
                             :: "v"(opA), "v"(p.u) : "memory");
            }
            unsigned long long* opB = (unsigned long long*)(h_exB + poff);
            __hip_atomic_store(opB, p.u, __ATOMIC_RELAXED,
                               __HIP_MEMORY_SCOPE_AGENT);
        }

        // off the critical path: tail collection + x bf16 conversion for t+1
        if (t >= T_ - LAST_) {
            f32x4* sp = (f32x4*)(hs + (size_t)(t - (T_ - LAST_)) * (B_ * H_)
                                    + hrow + n0 + q * 4);
            *sp = (f32x4){hm0, hm1, hm2, hm3};
        }
        #pragma unroll
        for (int c = 0; c < 4; ++c) {
            bf16x8 f;
            #pragma unroll
            for (int j = 0; j < 4; ++j) {
                f[j]     = (__bf16)xn[2 * c][j];
                f[j + 4] = (__bf16)xn[2 * c + 1][j];
            }
            xf[c] = f;
        }
    }
}

// Readout: out[b,:] = cat(hs)[b,:] @ W + bias.  One block per batch row.
__global__ __launch_bounds__(256) void esn_out(
    const float* __restrict__ hs, const float* __restrict__ Wm,
    const float* __restrict__ bias, float* __restrict__ out)
{
    const int b   = (int)blockIdx.x;
    const int tid = (int)threadIdx.x;
    float acc[O_];
    #pragma unroll
    for (int o = 0; o < O_; ++o) acc[o] = 0.f;

    for (int k = tid; k < LAST_ * H_; k += 256) {
        // cat order: k = t'*H + c  <->  hs[t'][b][c]
        const float hv = hs[(size_t)(k >> 10) * (B_ * H_) + (size_t)b * H_ + (k & (H_ - 1))];
        const f32x4* wp = (const f32x4*)(Wm + (size_t)k * O_);
        #pragma unroll
        for (int v = 0; v < 8; ++v) {
            f32x4 w4 = wp[v];
            acc[4 * v + 0] = fmaf(hv, w4[0], acc[4 * v + 0]);
            acc[4 * v + 1] = fmaf(hv, w4[1], acc[4 * v + 1]);
            acc[4 * v + 2] = fmaf(hv, w4[2], acc[4 * v + 2]);
            acc[4 * v + 3] = fmaf(hv, w4[3], acc[4 * v + 3]);
        }
    }

    __shared__ float red[256][O_ + 1];  // +1 pad: conflict-free column sums
    #pragma unroll
    for (int o = 0; o < O_; ++o) red[tid][o] = acc[o];
    __syncthreads();
    if (tid < O_) {
        float s = bias[tid];
        for (int i = 0; i < 256; ++i) s += red[i][tid];
        out[(size_t)b * O_ + tid] = s;
    }
}

extern "C" void kernel_launch(void* const* d_in, const int* in_sizes, int n_in,
                              void* d_out, int out_size, void* d_ws, size_t ws_size,
                              hipStream_t stream)
{
    const float* x    = (const float*)d_in[0];  // [128,2048,128]
    const float* w_in = (const float*)d_in[1];  // [128,1024]
    const float* w_r  = (const float*)d_in[2];  // [1024,1024]
    const float* Wm   = (const float*)d_in[3];  // [20480,32]
    const float* bias = (const float*)d_in[4];  // [32]
    float* out        = (float*)d_out;          // [128,32]

    const size_t flag_bytes = 4096;                                      // 128 ints used
    const size_t ring_bytes = (size_t)RING_ * B_ * H_ * sizeof(__bf16);  // 1 MiB each
    const size_t hs_bytes   = (size_t)LAST_ * B_ * H_ * sizeof(float);   // 10 MiB
    if (ws_size < flag_bytes + 2 * ring_bytes + hs_bytes) return;  // fail loud

    int*    flags = (int*)d_ws;
    __bf16* h_exA = (__bf16*)((char*)d_ws + flag_bytes);
    __bf16* h_exB = (__bf16*)((char*)d_ws + flag_bytes + ring_bytes);
    float*  hs    = (float*)((char*)d_ws + flag_bytes + 2 * ring_bytes);

    // flags = 0 (no XCD votes yet; 0 fails the 0x5A5A pattern check).
    // Rings = 0xAA: tag bit 0 = 0 = stale for t=0 (t=0 publishes tag 1).
    hipMemsetAsync(flags, 0x00, flag_bytes, stream);
    hipMemsetAsync(h_exA, 0xAA, 2 * ring_bytes, stream);

    hipLaunchKernelGGL(esn_persist, dim3(NB_ * NC_), dim3(256), 0, stream,
                       x, w_in, w_r, h_exA, h_exB, hs, flags);
    hipLaunchKernelGGL(esn_out, dim3(B_), dim3(256), 0, stream,
                       hs, Wm, bias, out);
}

// Round 7
// 6197.034 us; speedup vs baseline: 1.1335x; 1.0572x over previous
//
#include <hip/hip_runtime.h>
#include <stdint.h>
#include <stddef.h>

// Problem constants (ESN_58317065945127)
#define B_    128
#define T_    2048
#define D_    128
#define H_    1024
#define O_    32
#define LAST_ 20

// Partition: 8 batch-blocks x 16 col-blocks = 128 WGs of 256 threads.
#define NB_   8
#define NC_   16
#define RING_ 4
#define TWARM_ 8      // steps [1,TWARM): ring B (sc1) exchange; >=TWARM: ring A only

typedef __bf16 bf16x8 __attribute__((ext_vector_type(8)));
typedef __bf16 bf16x4 __attribute__((ext_vector_type(4)));
typedef float  f32x4  __attribute__((ext_vector_type(4)));
typedef unsigned int u32x4 __attribute__((ext_vector_type(4)));

union Pack8  { unsigned long long u;    bf16x4 v; };
union Pack16 { unsigned long long u[2]; u32x4 d; bf16x8 v; };

__device__ __forceinline__ float tanh_fast(float s) {
    float a = fminf(fmaxf(s, -12.0f), 12.0f);
    float e = __expf(2.0f * a);
    return (e - 1.0f) / (e + 1.0f);
}

// R11: KILL THE STEADY-STATE SC1 WRITES.
//
// R10 post-mortem: all transports (LLC full-poll / L2 full-poll / L2
// sentinel) pace at ~3us/step. Invariant across rounds: WRITE_SIZE = 535MB
// = exact ring-B publish volume; 256KB/step / 84GB/s = 3.05us = the step
// period. Agent-scope (sc1) publishes WRITE THROUGH TO DRAM as 8B scatter
// (each lane owns 8B) — HBM scatter-write tops out ~84GB/s — and every
// poll iteration's s_waitcnt vmcnt(0) waits on the wave's own outstanding
// publish store. The kernel was paced by the DRAM write-through drain, not
// by read latency. R8-R10's read-side work never touched the pacer.
//
// R11: steady state (votefast, t>=TWARM) publishes ONLY ring A via sc0
// (write-BACK into XCD L2, acks ~200cy, no DRAM). Ring B (sc1) written
// only for t<TWARM (its consumers read it) or if the XCD vote failed.
// Discovery: R10's sentinel-first machinery on ring A (one 8B word per
// producer wave), then one-shot 32KB fetch + per-word tag verify.
// Deadline (3s) is pure anti-hang; tag-gating keeps acceptance safe under
// any cache behavior (R8-R10 proved ring A serves: FETCH 346->87MB).
__global__ __launch_bounds__(256, 1) void esn_persist(
    const float* __restrict__ x, const float* __restrict__ w_in,
    const float* __restrict__ w_r, __bf16* __restrict__ h_exA,
    __bf16* __restrict__ h_exB, float* __restrict__ hs,
    int* __restrict__ flags)
{
    __shared__ bf16x8 ls[2][16][128];   // 2 bufs x 16 batch-rows x 128 16B chunks = 64 KiB

    const int wg  = (int)blockIdx.x;
    const int bb  = wg & (NB_ - 1);  // cohort id (batch block)
    const int cb  = wg >> 3;
    const int tid = (int)threadIdx.x;
    const int wv  = tid >> 6;
    const int ln  = tid & 63;
    const int nn  = ln & 15;   // batch index within tile
    const int q   = ln >> 4;   // quad
    const int b0  = bb * 16;
    const int n0  = cb * 64 + wv * 16;

    // Spin deadline ~3s (anti-hang only; tags make acceptance safe).
    const unsigned long long tdead =
        __builtin_amdgcn_s_memrealtime() + 300000000ull;

    // ---- XCD detection, publish leg ----
    int xcc;
    asm volatile("s_getreg_b32 %0, hwreg(HW_REG_XCC_ID)" : "=s"(xcc));
    const int mytag = 0x5A5A0000 | (xcc & 0xFF);
    if (tid == 0)
        __hip_atomic_store(flags + wg, mytag, __ATOMIC_RELAXED,
                           __HIP_MEMORY_SCOPE_AGENT);

    // ---- one-time: weight fragments into registers (A-operand layout) ----
    bf16x8 win[4];                       // w_in cols, K=128 -> 4 chunks
    #pragma unroll
    for (int c = 0; c < 4; ++c) {
        bf16x8 f;
        #pragma unroll
        for (int j = 0; j < 8; ++j)
            f[j] = (__bf16)w_in[(size_t)(c * 32 + q * 8 + j) * H_ + (n0 + nn)];
        win[c] = f;
    }
    bf16x8 wr[32];                       // w_r cols, K=1024 -> 32 chunks (128 regs)
    #pragma unroll
    for (int kc = 0; kc < 32; ++kc) {
        bf16x8 f;
        #pragma unroll
        for (int j = 0; j < 8; ++j)
            f[j] = (__bf16)w_r[(size_t)(kc * 32 + q * 8 + j) * H_ + (n0 + nn)];
        wr[kc] = f;
    }

    // ---- XCD detection, collect leg: unanimous vote enables ring A ----
    bool votefast;
    {
        int alleq = 0;
        for (;;) {
            int seen = 1; alleq = 1;
            #pragma unroll
            for (int k = 0; k < NC_; ++k) {
                int v = __hip_atomic_load(flags + (bb + 8 * k), __ATOMIC_RELAXED,
                                          __HIP_MEMORY_SCOPE_AGENT);
                seen  &= (int)((v & 0xFFFF0000) == 0x5A5A0000);
                alleq &= (int)(v == mytag);
            }
            if (seen) break;
            __builtin_amdgcn_s_sleep(8);
            if (__builtin_amdgcn_s_memrealtime() > tdead) { alleq = 0; break; }
        }
        votefast = (alleq != 0);
    }

    const float* xrow = x + (size_t)(b0 + nn) * T_ * D_ + q * 8;  // x[b][t][k]
    const size_t hrow = (size_t)(b0 + nn) * H_;

    // sentinel element offset within a ring slot's cohort block:
    // row 15, col (ln>>2)*64 + (ln&3)*16 + 12  (the q=3 word of producer
    // wave (cb'=ln>>2, wv'=ln&3), written by its lane 63). 8B-aligned.
    const int scol = (ln >> 2) * 64 + (ln & 3) * 16 + 12;

    // x prefetch (distance 1): xn = fp32 for step t+1, xf = bf16 frags for t
    f32x4 xn[8];
    bf16x8 xf[4];
    {
        #pragma unroll
        for (int c = 0; c < 4; ++c) {
            xn[2 * c]     = *(const f32x4*)(xrow + c * 32);
            xn[2 * c + 1] = *(const f32x4*)(xrow + c * 32 + 4);
        }
        #pragma unroll
        for (int c = 0; c < 4; ++c) {
            bf16x8 f;
            #pragma unroll
            for (int j = 0; j < 4; ++j) {
                f[j]     = (__bf16)xn[2 * c][j];
                f[j + 4] = (__bf16)xn[2 * c + 1][j];
            }
            xf[c] = f;
        }
    }

    float hm0 = 0.f, hm1 = 0.f, hm2 = 0.f, hm3 = 0.f;  // fp32 master h

    for (int t = 0; t < T_; ++t) {
        // issue x loads for t+1 NOW (fly during poll + compute)
        {
            const int tn = (t + 1 < T_) ? t + 1 : T_ - 1;
            const float* xp = xrow + (size_t)tn * D_;
            #pragma unroll
            for (int c = 0; c < 4; ++c) {
                xn[2 * c]     = *(const f32x4*)(xp + c * 32);
                xn[2 * c + 1] = *(const f32x4*)(xp + c * 32 + 4);
            }
        }

        f32x4 acc[8];
        #pragma unroll
        for (int i = 0; i < 8; ++i) acc[i] = (f32x4){0.f, 0.f, 0.f, 0.f};

        // x-projection MFMAs first: independent of the exchange.
        #pragma unroll
        for (int c = 0; c < 4; ++c)
            acc[c] = __builtin_amdgcn_mfma_f32_16x16x32_bf16(win[c], xf[c], acc[c], 0, 0, 0);

        if (t > 0) {
            const unsigned long long want1 =
                (unsigned long long)((((t - 1) >> 2) & 1) ^ 1) * 0x100000001ull;
            const int sb = (t - 1) & 1;
            const size_t slotoff =
                (size_t)((t - 1) & (RING_ - 1)) * (B_ * H_) + (size_t)b0 * H_;
            Pack16 pk[8];

            if (votefast && t >= TWARM_) {
                // ---- phase 1: sentinel poll on ring A (8B/lane) ----
                {
                    const unsigned long long* sp = (const unsigned long long*)
                        (h_exA + slotoff + 15 * H_ + scol);
                    int spins = 0;
                    for (;;) {
                        unsigned long long s;
                        asm volatile("global_load_dwordx2 %0, %1, off sc0 nt"
                                     : "=v"(s) : "v"(sp) : "memory");
                        asm volatile("s_waitcnt vmcnt(0)" : "+v"(s) :: "memory");
                        if (__all(((s ^ want1) & 0x100000001ull) == 0)) break;
                        if (((++spins) & 255) == 0 &&
                            __builtin_amdgcn_s_memrealtime() > tdead) break;
                    }
                }
                // ---- phase 2: one-shot 32KB fetch + per-word tag verify ----
                {
                    int spins = 0;
                    for (;;) {
                        #pragma unroll
                        for (int i = 0; i < 8; ++i) {
                            const int p = wv * 512 + i * 64 + ln;   // 16B piece
                            const __bf16* gp = h_exA + slotoff
                                + (size_t)(p >> 7) * H_ + (p & 127) * 8;
                            asm volatile("global_load_dwordx4 %0, %1, off sc0 nt"
                                         : "=v"(pk[i].d) : "v"(gp) : "memory");
                        }
                        asm volatile("s_waitcnt vmcnt(0)"
                                     : "+v"(pk[0].d), "+v"(pk[1].d), "+v"(pk[2].d),
                                       "+v"(pk[3].d), "+v"(pk[4].d), "+v"(pk[5].d),
                                       "+v"(pk[6].d), "+v"(pk[7].d) :: "memory");
                        __builtin_amdgcn_sched_barrier(0);
                        unsigned ok = 1u;
                        #pragma unroll
                        for (int i = 0; i < 8; ++i) {
                            ok &= (unsigned)(((pk[i].u[0] ^ want1) & 0x100000001ull) == 0);
                            ok &= (unsigned)(((pk[i].u[1] ^ want1) & 0x100000001ull) == 0);
                        }
                        if (__all(ok != 0u)) break;
                        if (((++spins) & 63) == 0 &&
                            __builtin_amdgcn_s_memrealtime() > tdead) break;  // anti-hang
                    }
                }
            } else {
                // ---- warmup / no-vote: ring B full poll (R6-proven) ----
                const __bf16* hbase = h_exB + slotoff;
                int spins = 0;
                for (;;) {
                    #pragma unroll
                    for (int i = 0; i < 8; ++i) {
                        const int p = wv * 512 + i * 64 + ln;
                        const unsigned long long* gp = (const unsigned long long*)
                            (hbase + (size_t)(p >> 7) * H_ + (p & 127) * 8);
                        pk[i].u[0] = __hip_atomic_load(gp, __ATOMIC_RELAXED,
                                                       __HIP_MEMORY_SCOPE_AGENT);
                        pk[i].u[1] = __hip_atomic_load(gp + 1, __ATOMIC_RELAXED,
                                                       __HIP_MEMORY_SCOPE_AGENT);
                    }
                    unsigned ok = 1u;
                    #pragma unroll
                    for (int i = 0; i < 8; ++i) {
                        ok &= (unsigned)(((pk[i].u[0] ^ want1) & 0x100000001ull) == 0);
                        ok &= (unsigned)(((pk[i].u[1] ^ want1) & 0x100000001ull) == 0);
                    }
                    if (__all(ok != 0u)) break;
                    __builtin_amdgcn_s_sleep(1);
                    if (((++spins) & 63) == 0 &&
                        __builtin_amdgcn_s_memrealtime() > tdead) break;  // anti-hang
                }
            }

            // ---- stage the loaded quarter into LDS, XOR swizzle ----
            #pragma unroll
            for (int i = 0; i < 8; ++i) {
                const int p = wv * 512 + i * 64 + ln;
                const int r = p >> 7, ch = p & 127;
                ls[sb][r][ch ^ (r & 7)] = pk[i].v;
            }

            __syncthreads();

            // ---- recurrent MFMAs from LDS, 8 accumulator chains ----
            #pragma unroll
            for (int kc = 0; kc < 32; ++kc) {
                bf16x8 a = ls[sb][nn][(kc * 4 + q) ^ (nn & 7)];
                acc[kc & 7] = __builtin_amdgcn_mfma_f32_16x16x32_bf16(wr[kc], a, acc[kc & 7], 0, 0, 0);
            }
        }

        const f32x4 asum = ((acc[0] + acc[4]) + (acc[1] + acc[5]))
                         + ((acc[2] + acc[6]) + (acc[3] + acc[7]));
        const float th0 = tanh_fast(asum[0]);
        const float th1 = tanh_fast(asum[1]);
        const float th2 = tanh_fast(asum[2]);
        const float th3 = tanh_fast(asum[3]);
        if (t == 0) {           // reference: h = tanh(xw[:,0]), no leak at t=0
            hm0 = th0; hm1 = th1; hm2 = th2; hm3 = th3;
        } else {                // h = 0.1*h + 0.9*tanh(.)
            hm0 = 0.1f * hm0 + 0.9f * th0;
            hm1 = 0.1f * hm1 + 0.9f * th1;
            hm2 = 0.1f * hm2 + 0.9f * th2;
            hm3 = 0.1f * hm3 + 0.9f * th3;
        }

        // publish 8B slice, lap tag in bit 0 of BOTH dwords — fire and forget.
        // Steady state: ring A ONLY (sc0 write-back L2 — no DRAM drain).
        // Ring B (sc1, DRAM write-through) only while its consumers exist.
        {
            Pack8 p;
            p.v = (bf16x4){(__bf16)hm0, (__bf16)hm1, (__bf16)hm2, (__bf16)hm3};
            const unsigned long long tg =
                (unsigned long long)(((t >> 2) & 1) ^ 1) * 0x100000001ull;
            p.u = (p.u & ~0x100000001ull) | tg;
            const size_t poff = (size_t)(t & (RING_ - 1)) * (B_ * H_)
                                + hrow + n0 + q * 4;
            if (votefast) {
                unsigned long long* opA = (unsigned long long*)(h_exA + poff);
                asm volatile("global_store_dwordx2 %0, %1, off sc0"
                             :: "v"(opA), "v"(p.u) : "memory");
                if (t < TWARM_) {
                    unsigned long long* opB = (unsigned long long*)(h_exB + poff);
                    __hip_atomic_store(opB, p.u, __ATOMIC_RELAXED,
                                       __HIP_MEMORY_SCOPE_AGENT);
                }
            } else {
                unsigned long long* opB = (unsigned long long*)(h_exB + poff);
                __hip_atomic_store(opB, p.u, __ATOMIC_RELAXED,
                                   __HIP_MEMORY_SCOPE_AGENT);
            }
        }

        // off the critical path: tail collection + x bf16 conversion for t+1
        if (t >= T_ - LAST_) {
            f32x4* sp = (f32x4*)(hs + (size_t)(t - (T_ - LAST_)) * (B_ * H_)
                                    + hrow + n0 + q * 4);
            *sp = (f32x4){hm0, hm1, hm2, hm3};
        }
        #pragma unroll
        for (int c = 0; c < 4; ++c) {
            bf16x8 f;
            #pragma unroll
            for (int j = 0; j < 4; ++j) {
                f[j]     = (__bf16)xn[2 * c][j];
                f[j + 4] = (__bf16)xn[2 * c + 1][j];
            }
            xf[c] = f;
        }
    }
}

// Readout: out[b,:] = cat(hs)[b,:] @ W + bias.  One block per batch row.
__global__ __launch_bounds__(256) void esn_out(
    const float* __restrict__ hs, const float* __restrict__ Wm,
    const float* __restrict__ bias, float* __restrict__ out)
{
    const int b   = (int)blockIdx.x;
    const int tid = (int)threadIdx.x;
    float acc[O_];
    #pragma unroll
    for (int o = 0; o < O_; ++o) acc[o] = 0.f;

    for (int k = tid; k < LAST_ * H_; k += 256) {
        // cat order: k = t'*H + c  <->  hs[t'][b][c]
        const float hv = hs[(size_t)(k >> 10) * (B_ * H_) + (size_t)b * H_ + (k & (H_ - 1))];
        const f32x4* wp = (const f32x4*)(Wm + (size_t)k * O_);
        #pragma unroll
        for (int v = 0; v < 8; ++v) {
            f32x4 w4 = wp[v];
            acc[4 * v + 0] = fmaf(hv, w4[0], acc[4 * v + 0]);
            acc[4 * v + 1] = fmaf(hv, w4[1], acc[4 * v + 1]);
            acc[4 * v + 2] = fmaf(hv, w4[2], acc[4 * v + 2]);
            acc[4 * v + 3] = fmaf(hv, w4[3], acc[4 * v + 3]);
        }
    }

    __shared__ float red[256][O_ + 1];  // +1 pad: conflict-free column sums
    #pragma unroll
    for (int o = 0; o < O_; ++o) red[tid][o] = acc[o];
    __syncthreads();
    if (tid < O_) {
        float s = bias[tid];
        for (int i = 0; i < 256; ++i) s += red[i][tid];
        out[(size_t)b * O_ + tid] = s;
    }
}

extern "C" void kernel_launch(void* const* d_in, const int* in_sizes, int n_in,
                              void* d_out, int out_size, void* d_ws, size_t ws_size,
                              hipStream_t stream)
{
    const float* x    = (const float*)d_in[0];  // [128,2048,128]
    const float* w_in = (const float*)d_in[1];  // [128,1024]
    const float* w_r  = (const float*)d_in[2];  // [1024,1024]
    const float* Wm   = (const float*)d_in[3];  // [20480,32]
    const float* bias = (const float*)d_in[4];  // [32]
    float* out        = (float*)d_out;          // [128,32]

    const size_t flag_bytes = 4096;                                      // 128 ints used
    const size_t ring_bytes = (size_t)RING_ * B_ * H_ * sizeof(__bf16);  // 1 MiB each
    const size_t hs_bytes   = (size_t)LAST_ * B_ * H_ * sizeof(float);   // 10 MiB
    if (ws_size < flag_bytes + 2 * ring_bytes + hs_bytes) return;  // fail loud

    int*    flags = (int*)d_ws;
    __bf16* h_exA = (__bf16*)((char*)d_ws + flag_bytes);
    __bf16* h_exB = (__bf16*)((char*)d_ws + flag_bytes + ring_bytes);
    float*  hs    = (float*)((char*)d_ws + flag_bytes + 2 * ring_bytes);

    // flags = 0 (no XCD votes yet; 0 fails the 0x5A5A pattern check).
    // Rings = 0xAA: tag bit 0 = 0 = stale for t=0 (t=0 publishes tag 1).
    hipMemsetAsync(flags, 0x00, flag_bytes, stream);
    hipMemsetAsync(h_exA, 0xAA, 2 * ring_bytes, stream);

    hipLaunchKernelGGL(esn_persist, dim3(NB_ * NC_), dim3(256), 0, stream,
                       x, w_in, w_r, h_exA, h_exB, hs, flags);
    hipLaunchKernelGGL(esn_out, dim3(B_), dim3(256), 0, stream,
                       hs, Wm, bias, out);
}